// Round 16
// baseline (2401.627 us; speedup 1.0000x reference)
//
#include <hip/hip_runtime.h>

#define Bb 256
#define Tt 256
#define Dd 64
#define Hh 512
#define BH (Bb*Hh)
#define S1 6                       // h1 slots (L0 run-ahead 4)

typedef _Float16 half8 __attribute__((ext_vector_type(8)));
typedef float floatx4 __attribute__((ext_vector_type(4)));
typedef unsigned long long u64x2 __attribute__((ext_vector_type(2)));

__device__ __forceinline__ float sigm(float x) { return 1.0f/(1.0f + __expf(-x)); }
__device__ __forceinline__ float tanh_(float x) {
  if (x >  15.0f) return  1.0f;
  if (x < -15.0f) return -1.0f;
  float e = __expf(2.0f*x);
  return (e - 1.0f)/(e + 1.0f);
}

// Producer side: NON-RETURNING atomic exchange = write executed AT the LLC,
// value stays IN the Infinity Cache (no DRAM writethrough, no DRAM refetch
// for consumers). Result discarded -> compiler emits no-return atomic.
__device__ __forceinline__ void at_u64(_Float16* p, unsigned long long v) {
  (void)__hip_atomic_exchange((unsigned long long*)p, v, __ATOMIC_RELAXED, __HIP_MEMORY_SCOPE_AGENT);
}
__device__ __forceinline__ void at_flag(unsigned* p, unsigned v) {
  (void)__hip_atomic_exchange(p, v, __ATOMIC_RELAXED, __HIP_MEMORY_SCOPE_AGENT);
}
// Consumer side (proven): relaxed agent loads lower to sc0 sc1 (LLC-coherent).
__device__ __forceinline__ half8 ld_h8(const _Float16* p) {
  u64x2 t;
  t.x = __hip_atomic_load((const unsigned long long*)p,       __ATOMIC_RELAXED, __HIP_MEMORY_SCOPE_AGENT);
  t.y = __hip_atomic_load(((const unsigned long long*)p) + 1, __ATOMIC_RELAXED, __HIP_MEMORY_SCOPE_AGENT);
  return __builtin_bit_cast(half8, t);
}
__device__ __forceinline__ unsigned ld_flag(const unsigned* p) {
  return __hip_atomic_load(p, __ATOMIC_RELAXED, __HIP_MEMORY_SCOPE_AGENT);
}

// ---- forced-ILP batched loads: ALL issued, ONE wait, inside ONE asm (r11-proven) ----
#define LD16(A) \
    "global_load_dwordx4 %0, " A ", off sc0 sc1\n\t" \
    "global_load_dwordx4 %1, " A ", off offset:64 sc0 sc1\n\t" \
    "global_load_dwordx4 %2, " A ", off offset:128 sc0 sc1\n\t" \
    "global_load_dwordx4 %3, " A ", off offset:192 sc0 sc1\n\t" \
    "global_load_dwordx4 %4, " A ", off offset:256 sc0 sc1\n\t" \
    "global_load_dwordx4 %5, " A ", off offset:320 sc0 sc1\n\t" \
    "global_load_dwordx4 %6, " A ", off offset:384 sc0 sc1\n\t" \
    "global_load_dwordx4 %7, " A ", off offset:448 sc0 sc1\n\t" \
    "global_load_dwordx4 %8, " A ", off offset:512 sc0 sc1\n\t" \
    "global_load_dwordx4 %9, " A ", off offset:576 sc0 sc1\n\t" \
    "global_load_dwordx4 %10, " A ", off offset:640 sc0 sc1\n\t" \
    "global_load_dwordx4 %11, " A ", off offset:704 sc0 sc1\n\t" \
    "global_load_dwordx4 %12, " A ", off offset:768 sc0 sc1\n\t" \
    "global_load_dwordx4 %13, " A ", off offset:832 sc0 sc1\n\t" \
    "global_load_dwordx4 %14, " A ", off offset:896 sc0 sc1\n\t" \
    "global_load_dwordx4 %15, " A ", off offset:960 sc0 sc1\n\t"
#define LD16OUT(o) \
      "=&v"(o[0]),"=&v"(o[1]),"=&v"(o[2]),"=&v"(o[3]), \
      "=&v"(o[4]),"=&v"(o[5]),"=&v"(o[6]),"=&v"(o[7]), \
      "=&v"(o[8]),"=&v"(o[9]),"=&v"(o[10]),"=&v"(o[11]), \
      "=&v"(o[12]),"=&v"(o[13]),"=&v"(o[14]),"=&v"(o[15])

__device__ __forceinline__ void ld16_batch(const _Float16* p, half8 o[16]) {
  asm volatile(LD16("%16") "s_waitcnt vmcnt(0)"
    : LD16OUT(o) : "v"(p) : "memory");
}

// ws (halfs): h1e[S1*BH] | h2l[2*BH] | h2e[BH] | flags[512 u32]
// flags[g*32 + cgi] = epoch flag of block (group g, col-group cgi)
__global__ void init_kernel(unsigned long long* __restrict__ hz,
                            unsigned* __restrict__ flags) {
  const int j0 = blockIdx.x*blockDim.x + threadIdx.x;
  if (j0 < 512) flags[j0] = 0u;
  const int NZ = (S1 + 3)*BH/4;
  for (int j = j0; j < NZ; j += gridDim.x*blockDim.x) hz[j] = 0ull;
}

__global__ void __launch_bounds__(256, 1)
lstm_fused(const float* __restrict__ x,      // [B,T,D] fp32
           _Float16* __restrict__ hb,
           unsigned* __restrict__ flags,
           const float* __restrict__ Wih0, const float* __restrict__ Whh0,
           const float* __restrict__ bih0, const float* __restrict__ bhh0,
           const float* __restrict__ Wih1, const float* __restrict__ Whh1,
           const float* __restrict__ bih1, const float* __restrict__ bhh1,
           const float* __restrict__ fcw,  const float* __restrict__ fcb,
           float* __restrict__ out)
{
  extern __shared__ _Float16 lds[];   // 128 KiB W (lane-major frags) + 2 KiB stage

  const int tid = threadIdx.x;
  const int bid = blockIdx.x;
  const int grp = bid & 7;            // (layer,rgi) group
  const int lb  = grp >> 2;
  const int rgi = grp & 3;
  const int cgi = bid >> 3;           // 0..31 col-group (16 h-cols)
  const int hc0 = cgi * 16;
  const int r0  = rgi * 64;

  unsigned* const myexp = flags + grp*32 + cgi;

  _Float16* const h1e = hb;
  _Float16* const h2l = hb + S1*BH;
  _Float16* const h2e = hb + (S1 + 2)*BH;

  // ---- preload W slice (fp32 -> fp16) into lane-major fragment LDS (proven) ----
  {
    const float* Whh = lb ? Whh1 : Whh0;
    const float* Wih = lb ? Wih1 : Wih0;
    const int Kin = lb ? Hh : Dd;
    const int KT  = Hh + Kin;
    for (int idx = tid; idx < 64*KT; idx += 256) {
      const int gr = idx / KT;
      const int k  = idx - gr*KT;
      const int bt = gr >> 4, s = gr & 15;
      const int gate = (bt & 1)*2 + (s >> 3);
      const int hcc  = (bt >> 1)*8 + (s & 7);
      const int wrow = gate*Hh + hc0 + hcc;
      const float v = (k < Hh) ? Whh[(size_t)wrow*Hh + k]
                               : Wih[(size_t)wrow*Kin + (k - Hh)];
      const int li = (((k >> 5)*4 + bt) << 9) + ((((k >> 3) & 3)*16 + s) << 3) + (k & 7);
      lds[li] = (_Float16)v;
    }
  }
  __syncthreads();

  const int w    = tid >> 6;
  const int lane = tid & 63;
  const int kg   = lane >> 4;
  const int n15  = lane & 15;
  const bool lo  = (n15 < 8);
  const int rowb = r0 + w*16;

  const _Float16* const bfrag = lds + (lane << 3);   // + (ks*4+bt)*512
  _Float16* const stage = lds + 65536 + w*256;
  const size_t stoff = (size_t)(rowb + (lane >> 2))*Hh + hc0 + (lane & 3)*4;
  const size_t rowoff = (size_t)(rowb + n15)*Hh + 8*kg;

  const float* bi = lb ? bih1 : bih0;
  const float* bh = lb ? bhh1 : bhh0;
  float biasA[2], biasB[2];
  #pragma unroll
  for (int o = 0; o < 2; ++o) {
    const int hc = hc0 + o*8 + (n15 & 7);
    biasA[o] = lo ? (bi[hc]      + bh[hc])      : (bi[512+hc]  + bh[512+hc]);
    biasB[o] = lo ? (bi[1024+hc] + bh[1024+hc]) : (bi[1536+hc] + bh[1536+hc]);
  }

  float cst[2][4] = {{0.f,0.f,0.f,0.f},{0.f,0.f,0.f,0.f}};

  for (int i = 0; i <= Tt; ++i) {
    const bool active = lb ? (i >= 1) : (i < Tt);
    if (active) {
      floatx4 acc[4] = {};

      if (lb) {
        // ===== phase A (cross, usually pre-satisfied by L0 run-ahead) =====
        if (tid < 32) {
          const unsigned* fp = flags + (grp ^ 4)*32 + tid;
          while (!__all((int)(ld_flag(fp) >= (unsigned)i)))
            __builtin_amdgcn_s_sleep(1);
        }
        __syncthreads();
        __builtin_amdgcn_sched_barrier(0);
        {
          const _Float16* cp = h1e + (size_t)((i+S1-1)%S1)*BH + rowoff;
          half8 a2[16];
          ld16_batch(cp, a2);
          #pragma unroll
          for (int ks = 0; ks < 16; ++ks)
            #pragma unroll
            for (int bt = 0; bt < 4; ++bt)
              acc[bt] = __builtin_amdgcn_mfma_f32_16x16x32_f16(
                          a2[ks], *(const half8*)(bfrag + (((16+ks)*4 + bt) << 9)), acc[bt], 0,0,0);
        }
        // ===== phase B (self-recurrence: the critical chain) =====
        if (tid < 32) {
          const unsigned* fp = flags + grp*32 + tid;
          while (!__all((int)(ld_flag(fp) >= (unsigned)i)))
            __builtin_amdgcn_s_sleep(1);
        }
        __syncthreads();
        __builtin_amdgcn_sched_barrier(0);
        {
          const _Float16* ap = h2l + (size_t)((i+1)&1)*BH + rowoff;
          half8 a1[16];
          ld16_batch(ap, a1);
          #pragma unroll
          for (int ks = 0; ks < 16; ++ks)
            #pragma unroll
            for (int bt = 0; bt < 4; ++bt)
              acc[bt] = __builtin_amdgcn_mfma_f32_16x16x32_f16(
                          a1[ks], *(const half8*)(bfrag + ((ks*4 + bt) << 9)), acc[bt], 0,0,0);
        }
      } else {
        // x loads issue pre-poll (immutable, cached) and fly during the wait
        const float* xp = x + (((size_t)(rowb + n15)) << 14) + ((size_t)i << 6) + 8*kg;
        const floatx4 xa = *(const floatx4*)(xp);
        const floatx4 xb = *(const floatx4*)(xp + 4);
        const floatx4 xc = *(const floatx4*)(xp + 32);
        const floatx4 xd = *(const floatx4*)(xp + 36);
        // dual poll (self >= i; guard: L1 flags >= i-4)
        if (tid < 64) {
          const int m = tid & 31;
          const bool self = (tid < 32);
          const unsigned tgt = self ? (unsigned)i
                                    : ((i >= S1) ? (unsigned)(i - (S1 - 2)) : 0u);
          const unsigned* fp = flags + (self ? grp : (grp ^ 4))*32 + m;
          while (!__all((int)(ld_flag(fp) >= tgt)))
            __builtin_amdgcn_s_sleep(1);
        }
        __syncthreads();
        __builtin_amdgcn_sched_barrier(0);
        const _Float16* ap = h1e + (size_t)((i+S1-1)%S1)*BH + rowoff;
        half8 a1[16];
        ld16_batch(ap, a1);
        half8 a2[2];
        #pragma unroll
        for (int e = 0; e < 4; ++e) {
          a2[0][e] = (_Float16)xa[e]; a2[0][4+e] = (_Float16)xb[e];
          a2[1][e] = (_Float16)xc[e]; a2[1][4+e] = (_Float16)xd[e];
        }
        #pragma unroll
        for (int ks = 0; ks < 16; ++ks)
          #pragma unroll
          for (int bt = 0; bt < 4; ++bt)
            acc[bt] = __builtin_amdgcn_mfma_f32_16x16x32_f16(
                        a1[ks], *(const half8*)(bfrag + ((ks*4 + bt) << 9)), acc[bt], 0,0,0);
        #pragma unroll
        for (int ks = 0; ks < 2; ++ks)
          #pragma unroll
          for (int bt = 0; bt < 4; ++bt)
            acc[bt] = __builtin_amdgcn_mfma_f32_16x16x32_f16(
                        a2[ks], *(const half8*)(bfrag + (((16+ks)*4 + bt) << 9)), acc[bt], 0,0,0);
      }

      // pointwise: lanes n15<8 hold i,g; n15>=8 hold f,o (pair via lane^8); stage h
      #pragma unroll
      for (int o = 0; o < 2; ++o) {
        #pragma unroll
        for (int rr = 0; rr < 4; ++rr) {
          const float pA = acc[2*o][rr]   + biasA[o];
          const float pB = acc[2*o+1][rr] + biasB[o];
          const float v1 = sigm(pA);
          const float v2 = lo ? tanh_(pB) : sigm(pB);
          const float fs  = __shfl_xor(v1, 8, 64);
          const float os_ = __shfl_xor(v2, 8, 64);
          if (lo) {
            const float c = fs * cst[o][rr] + v1 * v2;
            cst[o][rr] = c;
            stage[(kg*4 + rr)*16 + o*8 + (n15 & 7)] = (_Float16)(os_ * tanh_(c));
          }
        }
      }
      asm volatile("s_waitcnt lgkmcnt(0)" ::: "memory");
      __builtin_amdgcn_sched_barrier(0);
      const unsigned long long pk = *(const unsigned long long*)(stage + (lane << 2));

      if (!lb) {
        at_u64(h1e + (size_t)(i%S1)*BH + stoff, pk);     // lands IN the LLC
      } else {
        at_u64(h2l + (size_t)(i&1)*BH + stoff, pk);
        if (i == Tt) at_u64(h2e + stoff, pk);
      }
    } // active

    // ---- release (every iter, proven): drain, sync, publish epoch ----
    asm volatile("s_waitcnt vmcnt(0)" ::: "memory");
    __syncthreads();
    if (tid == 0) at_flag(myexp, (unsigned)(i + 1));
  }

  // ---- FC: out[b] = h2_final[b,:] . fcw + fcb ----
  if (bid == 0) {
    if (tid < 64) {
      const unsigned* f1 = flags + (4 + (tid >> 5))*32 + (tid & 31);  // groups 4,5
      const unsigned* f2 = f1 + 64;                                    // groups 6,7
      while (1) {
        int ok = (ld_flag(f1) > (unsigned)Tt) & (ld_flag(f2) > (unsigned)Tt);
        if (__all(ok)) break;
        __builtin_amdgcn_s_sleep(1);
      }
    }
    __syncthreads();
    asm volatile("" ::: "memory");
    float acc = fcb[0];
    for (int c = 0; c < 4; ++c) {
      half8 v[16];
      #pragma unroll
      for (int j = 0; j < 16; ++j)
        v[j] = ld_h8(h2e + (size_t)tid*Hh + c*128 + j*8);
      #pragma unroll
      for (int j = 0; j < 16; ++j)
        #pragma unroll
        for (int e = 0; e < 8; ++e)
          acc += (float)v[j][e] * fcw[c*128 + j*8 + e];
    }
    out[tid] = acc;
  }
}

extern "C" void kernel_launch(void* const* d_in, const int* in_sizes, int n_in,
                              void* d_out, int out_size, void* d_ws, size_t ws_size,
                              hipStream_t stream) {
  const float* x    = (const float*)d_in[0];
  const float* Wih0 = (const float*)d_in[1];
  const float* Whh0 = (const float*)d_in[2];
  const float* bih0 = (const float*)d_in[3];
  const float* bhh0 = (const float*)d_in[4];
  const float* Wih1 = (const float*)d_in[5];
  const float* Whh1 = (const float*)d_in[6];
  const float* bih1 = (const float*)d_in[7];
  const float* bhh1 = (const float*)d_in[8];
  const float* fcw  = (const float*)d_in[9];
  const float* fcb  = (const float*)d_in[10];
  float* out = (float*)d_out;

  _Float16* hb    = (_Float16*)d_ws;                          // (S1+3)*BH halfs
  unsigned* flags = (unsigned*)(hb + (size_t)(S1 + 3)*BH);    // 2 KiB

  hipFuncSetAttribute((const void*)lstm_fused,
                      hipFuncAttributeMaxDynamicSharedMemorySize, 133120);

  hipLaunchKernelGGL(init_kernel, dim3(512), dim3(256), 0, stream,
                     (unsigned long long*)hb, flags);

  hipLaunchKernelGGL(lstm_fused, dim3(256), dim3(256), 133120, stream,
                     x, hb, flags,
                     Wih0, Whh0, bih0, bhh0, Wih1, Whh1, bih1, bhh1, fcw, fcb, out);
}